// Round 2
// baseline (53358.557 us; speedup 1.0000x reference)
//
#include <hip/hip_runtime.h>
#include <stdint.h>

// Graves handwriting RNN: persistent-kernel implementation.
// B=128 T=600 U=50 H=400 V=80 K=10 OUT=121
#define BB   128
#define TT   600
#define UU   50
#define HH   400
#define VV   80
#define KA   10
#define OD   121
#define NBLK 200      // grid blocks; block owns 2 n-columns (400 n / 200)
#define KPAD 484      // 3(x) + 80(w) + 400(h) + 1 pad

// ---------------- workspace layout (bytes) ----------------
// Wt    : [400][484][4] f32  (weights transposed, gate-packed)  3,097,600
// Wbias : [400][4] f32                                              6,400
// Woutp : [100][128] uint2 (bf16x4-packed W_out, k-major)         102,400
// h0,h1 : [128][400] f32 double buffer                        2 x 204,800
// wbuf  : [128][80] f32                                            40,960
// bar   : 1280 one-shot counters, 64B apart                        81,920
#define OFF_WT    0
#define OFF_WB    3097600
#define OFF_WOP   3104000
#define OFF_H0    3206400
#define OFF_H1    3411200
#define OFF_WBUF  3616000
#define OFF_BAR   3656960

__device__ __forceinline__ float sigm(float v)   { return 1.f / (1.f + __expf(-v)); }
__device__ __forceinline__ float tanh_f(float v) { return 1.f - 2.f / (__expf(2.f * v) + 1.f); }

__device__ __forceinline__ unsigned bfr(float f) {
    unsigned u = __float_as_uint(f);
    unsigned r = (u + 0x7fffu + ((u >> 16) & 1u)) >> 16;   // RNE bf16
    return r & 0xffffu;
}

// one-shot grid barrier: unique counter per sync point
__device__ __forceinline__ void bar_arrive(int* bar, int id) {
    __threadfence();                 // make this thread's global stores device-visible
    __syncthreads();                 // all threads of block fenced
    if (threadIdx.x == 0)
        __hip_atomic_fetch_add(&bar[id * 16], 1, __ATOMIC_RELEASE, __HIP_MEMORY_SCOPE_AGENT);
}
__device__ __forceinline__ void bar_wait(int* bar, int id) {
    if (threadIdx.x == 0) {
        while (__hip_atomic_load(&bar[id * 16], __ATOMIC_ACQUIRE, __HIP_MEMORY_SCOPE_AGENT) < NBLK)
            __builtin_amdgcn_s_sleep(1);
    }
    __syncthreads();
}

// ---------------- setup: transpose/pack weights, zero state ----------------
__global__ void setup_kernel(const float* __restrict__ W_ih, const float* __restrict__ W_hh,
                             const float* __restrict__ b_lstm, const float* __restrict__ W_out,
                             float* __restrict__ Wt, float* __restrict__ Wbias,
                             uint2* __restrict__ Woutp,
                             float* __restrict__ h0, float* __restrict__ h1,
                             float* __restrict__ wbuf, int* __restrict__ bar)
{
    const int NT1 = 400 * KPAD * 4;       // 774400
    const int NT2 = 1600;
    const int NT3 = 100 * 128;            // 12800
    const int NZ1 = 51200, NZ2 = 51200, NZ3 = 10240, NZ4 = 1280 * 16;
    const int total = NT1 + NT2 + NT3 + NZ1 + NZ2 + NZ3 + NZ4;
    for (int i = blockIdx.x * blockDim.x + threadIdx.x; i < total; i += gridDim.x * blockDim.x) {
        int idx = i;
        if (idx < NT1) {
            int n = idx / (KPAD * 4);
            int r = idx - n * (KPAD * 4);
            int k = r >> 2, g = r & 3;
            int col = g * 400 + n;
            float v = 0.f;
            if (k < 83)       v = W_ih[k * 1600 + col];          // rows 0..2 = x, 3..82 = w
            else if (k < 483) v = W_hh[(k - 83) * 1600 + col];   // rows 83..482 = h
            Wt[idx] = v;
            continue;
        }
        idx -= NT1;
        if (idx < NT2) {
            int n = idx >> 2, g = idx & 3;
            Wbias[idx] = b_lstm[g * 400 + n];
            continue;
        }
        idx -= NT2;
        if (idx < NT3) {
            int kq = idx / 128, o = idx & 127;
            uint2 v; v.x = 0u; v.y = 0u;
            if (o < OD) {
                unsigned r0 = bfr(W_out[(4 * kq + 0) * OD + o]);
                unsigned r1 = bfr(W_out[(4 * kq + 1) * OD + o]);
                unsigned r2 = bfr(W_out[(4 * kq + 2) * OD + o]);
                unsigned r3 = bfr(W_out[(4 * kq + 3) * OD + o]);
                v.x = r0 | (r1 << 16);
                v.y = r2 | (r3 << 16);
            }
            Woutp[idx] = v;
            continue;
        }
        idx -= NT3;
        if (idx < NZ1) { h0[idx] = 0.f; continue; }
        idx -= NZ1;
        if (idx < NZ2) { h1[idx] = 0.f; continue; }
        idx -= NZ2;
        if (idx < NZ3) { wbuf[idx] = 0.f; continue; }
        idx -= NZ3;
        bar[idx] = 0;
    }
}

// ---------------- main persistent kernel ----------------
__global__ __launch_bounds__(256) void rnn_main(
    const float* __restrict__ x, const int* __restrict__ c, const int* __restrict__ c_len,
    const float* __restrict__ W_attn, const float* __restrict__ b_attn,
    const float* __restrict__ b_out,
    const float* __restrict__ Wt, const float* __restrict__ Wbias,
    const uint2* __restrict__ Woutp,
    float* __restrict__ h0, float* __restrict__ h1, float* __restrict__ wbuf,
    int* __restrict__ bar, float* __restrict__ out)
{
    __shared__ float s_wattn[12000];   // [400][30]
    __shared__ float s_ap[32];
    __shared__ float s_abk[48];        // alpha@0, beta@16, kappa@32
    __shared__ float s_w[VV];
    __shared__ int   s_c[UU];

    const int bk  = blockIdx.x;
    const int tid = threadIdx.x;

    int clen = 0;
    if (bk < BB) {
        for (int i = tid; i < 12000; i += 256) s_wattn[i] = W_attn[i];
        if (tid < 16) s_abk[32 + tid] = 0.f;                 // kappa state
        if (tid < UU) s_c[tid] = c[bk * UU + tid];
        clen = c_len[bk];
    }
    __syncthreads();

    // phase-A identity: thread -> (batch bb, n-column n)
    const int nn  = tid >> 7;          // wave-uniform (waves 0,1 -> 0; waves 2,3 -> 1)
    const int bb  = tid & 127;
    const int n   = bk * 2 + nn;
    const int n_u = __builtin_amdgcn_readfirstlane(n);
    const float4* Wq = (const float4*)(Wt + (size_t)n_u * (KPAD * 4));
    const float4 bias = ((const float4*)Wbias)[n_u];
    float cs = 0.f;                    // cell state, register-resident for all 600 steps

    // out-projection identity for blocks 128..199
    float bo_ = 0.f; int ob = 0, oo = 0;
    const int oidx = (bk - BB) * 216 + tid;
    const bool odo = (bk >= BB) && (tid < 216) && (oidx < BB * OD);
    if (odo) { ob = oidx / OD; oo = oidx - ob * OD; bo_ = b_out[oo]; }

    int barid = 0;
    for (int t = 0; t < TT; t++) {
        const float* hcur  = (t & 1) ? h1 : h0;
        float*       hnext = (t & 1) ? h0 : h1;

        // ================= phase A: z-GEMM + LSTM elementwise =================
        float ai = bias.x, af = bias.y, ag = bias.z, ao = bias.w;
        {
            const float* xb = x + ((size_t)bb * TT + t) * 3;
            float x0 = xb[0], x1 = xb[1], x2 = xb[2];
            float4 w0 = Wq[0], w1 = Wq[1], w2 = Wq[2];
            ai += x0 * w0.x + x1 * w1.x + x2 * w2.x;
            af += x0 * w0.y + x1 * w1.y + x2 * w2.y;
            ag += x0 * w0.z + x1 * w1.z + x2 * w2.z;
            ao += x0 * w0.w + x1 * w1.w + x2 * w2.w;

            const float4* wrow = (const float4*)(wbuf + bb * VV);
            #pragma unroll 5
            for (int q = 0; q < 20; q++) {
                float4 cv = wrow[q];
                float4 wa = Wq[3 + 4 * q], wb_ = Wq[4 + 4 * q], wc = Wq[5 + 4 * q], wd = Wq[6 + 4 * q];
                ai += cv.x * wa.x + cv.y * wb_.x + cv.z * wc.x + cv.w * wd.x;
                af += cv.x * wa.y + cv.y * wb_.y + cv.z * wc.y + cv.w * wd.y;
                ag += cv.x * wa.z + cv.y * wb_.z + cv.z * wc.z + cv.w * wd.z;
                ao += cv.x * wa.w + cv.y * wb_.w + cv.z * wc.w + cv.w * wd.w;
            }
            const float4* hrow = (const float4*)(hcur + bb * HH);
            #pragma unroll 5
            for (int q = 0; q < 100; q++) {
                float4 cv = hrow[q];
                float4 wa = Wq[83 + 4 * q], wb_ = Wq[84 + 4 * q], wc = Wq[85 + 4 * q], wd = Wq[86 + 4 * q];
                ai += cv.x * wa.x + cv.y * wb_.x + cv.z * wc.x + cv.w * wd.x;
                af += cv.x * wa.y + cv.y * wb_.y + cv.z * wc.y + cv.w * wd.y;
                ag += cv.x * wa.z + cv.y * wb_.z + cv.z * wc.z + cv.w * wd.z;
                ao += cv.x * wa.w + cv.y * wb_.w + cv.z * wc.w + cv.w * wd.w;
            }
        }
        {
            float si = sigm(ai), sf = sigm(af), so = sigm(ao);
            cs = sf * cs + si * tanh_f(ag);
            float hv = so * tanh_f(cs);
            hnext[bb * HH + n] = hv;
        }

        bar_arrive(bar, barid); bar_wait(bar, barid); barid++;

        // ================= phase B: attention (blocks 0..127) | out-proj (128..199) =================
        if (bk < BB) {
            const float* hb = hnext + bk * HH;
            float part = 0.f;
            int j = tid >> 3, ks = tid & 7;
            if (tid < 240) {
                for (int k2 = ks; k2 < HH; k2 += 8)
                    part += hb[k2] * s_wattn[k2 * 30 + j];
            }
            part += __shfl_down(part, 4, 8);
            part += __shfl_down(part, 2, 8);
            part += __shfl_down(part, 1, 8);
            if (tid < 240 && ks == 0) s_ap[j] = part + b_attn[j];
            __syncthreads();
            if (tid < KA) {
                s_abk[tid]      = __expf(s_ap[tid]);            // alpha
                s_abk[16 + tid] = __expf(s_ap[10 + tid]);       // beta
                s_abk[32 + tid] += __expf(s_ap[20 + tid]);      // kappa += exp(k_hat)
            }
            if (tid < VV) s_w[tid] = 0.f;
            __syncthreads();
            if (tid < UU && tid < clen) {
                float u = (float)tid;
                float phi = 0.f;
                #pragma unroll
                for (int jj = 0; jj < KA; jj++) {
                    float d = s_abk[32 + jj] - u;
                    phi += s_abk[jj] * __expf(-s_abk[16 + jj] * d * d);
                }
                atomicAdd(&s_w[s_c[tid]], phi);
            }
            __syncthreads();
            if (tid < VV) wbuf[bk * VV + tid] = s_w[tid];
        } else if (odo) {
            const float4* hb4 = (const float4*)(hnext + ob * HH);
            float acc = bo_;
            #pragma unroll 4
            for (int kq = 0; kq < 100; kq++) {
                uint2  wp  = Woutp[kq * 128 + oo];
                float4 hv4 = hb4[kq];
                acc += hv4.x * __uint_as_float(wp.x << 16)
                     + hv4.y * __uint_as_float(wp.x & 0xffff0000u)
                     + hv4.z * __uint_as_float(wp.y << 16)
                     + hv4.w * __uint_as_float(wp.y & 0xffff0000u);
            }
            out[((size_t)ob * TT + t) * OD + oo] = acc;
        }

        bar_arrive(bar, barid); bar_wait(bar, barid); barid++;
    }
}

extern "C" void kernel_launch(void* const* d_in, const int* in_sizes, int n_in,
                              void* d_out, int out_size, void* d_ws, size_t ws_size,
                              hipStream_t stream) {
    (void)in_sizes; (void)n_in; (void)out_size; (void)ws_size;
    const float* x      = (const float*)d_in[0];
    const int*   c      = (const int*)  d_in[1];
    // d_in[2] = x_len (unused by reference)
    const int*   c_len  = (const int*)  d_in[3];
    const float* W_ih   = (const float*)d_in[4];
    const float* W_hh   = (const float*)d_in[5];
    const float* b_lstm = (const float*)d_in[6];
    const float* W_attn = (const float*)d_in[7];
    const float* b_attn = (const float*)d_in[8];
    const float* W_out  = (const float*)d_in[9];
    const float* b_out  = (const float*)d_in[10];
    float* out = (float*)d_out;

    char* p = (char*)d_ws;
    float* Wt    = (float*)(p + OFF_WT);
    float* Wbias = (float*)(p + OFF_WB);
    uint2* Woutp = (uint2*)(p + OFF_WOP);
    float* h0    = (float*)(p + OFF_H0);
    float* h1    = (float*)(p + OFF_H1);
    float* wbuf  = (float*)(p + OFF_WBUF);
    int*   bar   = (int*)  (p + OFF_BAR);

    hipLaunchKernelGGL(setup_kernel, dim3(256), dim3(256), 0, stream,
                       W_ih, W_hh, b_lstm, W_out, Wt, Wbias, Woutp, h0, h1, wbuf, bar);
    hipLaunchKernelGGL(rnn_main, dim3(NBLK), dim3(256), 0, stream,
                       x, c, c_len, W_attn, b_attn, b_out, Wt, Wbias, Woutp,
                       h0, h1, wbuf, bar, out);
}

// Round 11
// 16830.688 us; speedup vs baseline: 3.1703x; 3.1703x over previous
//
#include <hip/hip_runtime.h>
#include <stdint.h>

// Graves handwriting RNN — batch-parallel persistent blocks, ZERO grid sync.
// Block b owns batch b's entire 600-step recurrence (batches independent).
// Weights fp16-packed. R10 post-mortem: bf16 (0.0703) vs fp16 (0.0723) absmax
// EQUAL -> error was precision-independent: an inter-wave RACE on q[83..482]
// (h written in-place in phase A while other waves still read it for the same
// step). Fixed with a reads-complete __syncthreads() before the h writeback.
// B=128 T=600 U=50 H=400 V=80 K=10 OUT=121
#define BB   128
#define TT   600
#define UU   50
#define VV   80
#define KA   10
#define OD   121
#define HH   400
#define NTH  1024
#define KQ   484      // concat dim: 3(x) + 80(w) + 400(h) + 1 pad
#define TPK  124      // uint4 per z-thread (121 used + 3 pad -> 64B-aligned 1984B)

// workspace layout (bytes)
// Wz : 800 threads * 124 uint4 * 16B = 1,587,200   (fp16x2-packed z-weights)
// Wo : 121*8*25 u32 * 4B            =    96,800    (fp16x2-packed W_out)
#define OFF_WZ   0
#define OFF_WO   1587200

__device__ __forceinline__ unsigned short f2h(float f) {     // fp32 -> fp16 (RNE)
    _Float16 h = (_Float16)f;
    unsigned short us; __builtin_memcpy(&us, &h, 2); return us;
}
__device__ __forceinline__ float hl(unsigned u) {            // low fp16 -> fp32
    unsigned short us = (unsigned short)(u & 0xffffu);
    _Float16 h; __builtin_memcpy(&h, &us, 2); return (float)h;
}
__device__ __forceinline__ float hh(unsigned u) {            // high fp16 -> fp32
    unsigned short us = (unsigned short)(u >> 16);
    _Float16 h; __builtin_memcpy(&h, &us, 2); return (float)h;
}
__device__ __forceinline__ float sigm(float v)   { return 1.f / (1.f + __expf(-v)); }
__device__ __forceinline__ float tanh_f(float v) { return 1.f - 2.f / (__expf(2.f * v) + 1.f); }

// ---------------- setup: pack weights to fp16 streams ----------------
__global__ void setup_kernel(const float* __restrict__ W_ih, const float* __restrict__ W_hh,
                             const float* __restrict__ W_out,
                             unsigned* __restrict__ Wz, unsigned* __restrict__ Wo)
{
    const int NWZ = 800 * 484;            // 800 threads * 121 uint4 * 4 u32
    const int NWO = 121 * 8 * 25;
    const int total = NWZ + NWO;
    for (int i = blockIdx.x * blockDim.x + threadIdx.x; i < total; i += gridDim.x * blockDim.x) {
        if (i < NWZ) {
            int tid = i / 484;
            int r   = i - tid * 484;
            int kk  = r >> 2, g = r & 3;
            int n   = tid >> 1, hf = tid & 1;
            int col = g * 400 + n;
            int k0  = hf * 242 + 2 * kk;
            int k1  = k0 + 1;
            // concat row mapping: 0..2 = x (W_ih rows 0..2), 3..82 = w (W_ih 3..82),
            // 83..482 = h (W_hh 0..399), 483 = zero pad
            float s0 = (k0 < 83) ? W_ih[k0 * 1600 + col] : (k0 < 483 ? W_hh[(k0 - 83) * 1600 + col] : 0.f);
            float s1 = (k1 < 83) ? W_ih[k1 * 1600 + col] : (k1 < 483 ? W_hh[(k1 - 83) * 1600 + col] : 0.f);
            Wz[(size_t)tid * (TPK * 4) + kk * 4 + g] = (unsigned)f2h(s0) | ((unsigned)f2h(s1) << 16);
        } else {
            int j = i - NWZ;
            int o = j / 200; int r = j - o * 200; int ks = r / 25; int m = r - ks * 25;
            int k0 = ks * 50 + 2 * m;
            Wo[o * 200 + ks * 25 + m] = (unsigned)f2h(W_out[k0 * OD + o])
                                      | ((unsigned)f2h(W_out[(k0 + 1) * OD + o]) << 16);
        }
    }
}

// ---------------- main: one block per batch, full 600-step loop ----------------
__global__ __launch_bounds__(NTH) void rnn_main(
    const float* __restrict__ x, const int* __restrict__ c, const int* __restrict__ c_len,
    const float* __restrict__ W_attn, const float* __restrict__ b_attn,
    const float* __restrict__ b_lstm, const float* __restrict__ b_out,
    const unsigned* __restrict__ Wz, const unsigned* __restrict__ Wo,
    float* __restrict__ out)
{
    __shared__ float s_wattn[12000];   // [400][30] fp32 (no precision loss, zero stream)
    __shared__ float q[KQ];            // [x3 | w80 | h400 | pad]
    __shared__ float h_s[HH];          // aligned h copy for phase B
    __shared__ float s_ap[32];
    __shared__ float s_abk[48];        // alpha@0 beta@16 kappa@32 (kappa persistent)
    __shared__ int   s_c[UU];

    const int b   = blockIdx.x;
    const int tid = threadIdx.x;

    for (int i = tid; i < 12000; i += NTH) s_wattn[i] = W_attn[i];
    if (tid < UU) s_c[tid] = c[b * UU + tid];
    if (tid < 16) s_abk[32 + tid] = 0.f;
    if (tid < KQ) q[tid] = (tid < 3) ? x[((size_t)b * TT + 0) * 3 + tid] : 0.f;
    const int clen = min(c_len[b], UU);

    // z-GEMV identity: tid<800 -> (n = tid>>1, half = tid&1), 242 k each, 4 gates
    const int  n   = tid >> 1;
    const bool zdo = (tid < 800);
    const uint4* wp = (const uint4*)Wz + (size_t)tid * TPK;
    float bi = 0.f, bfg = 0.f, bgg = 0.f, bog = 0.f;
    if (zdo && !(tid & 1)) {
        bi  = b_lstm[0 * 400 + n];
        bfg = b_lstm[1 * 400 + n];
        bgg = b_lstm[2 * 400 + n];
        bog = b_lstm[3 * 400 + n];
    }
    float cs = 0.f;                     // cell state, register-resident

    // attention identity: tid<240 -> (aj = tid>>3 in [0,30), aks = tid&7)
    const int  aj = tid >> 3, aks = tid & 7;
    const bool ado = (tid < 240);
    const float battn = (ado && aks == 0) ? b_attn[aj] : 0.f;

    // out-proj identity: tid<968 -> (oo = tid>>3 in [0,121), oks = tid&7)
    const int  oo = tid >> 3, oks = tid & 7;
    const bool odo = (tid < 968);
    const float bout = odo ? b_out[oo] : 0.f;
    const unsigned* wop = Wo + oo * 200 + oks * 25;

    __syncthreads();

    for (int t = 0; t < TT; ++t) {
        // ============ phase A: z = q @ Wz, LSTM elementwise ============
        float ai = 0.f, af = 0.f, ag = 0.f, ao = 0.f;
        if (zdo) {
            const float2* q2 = (const float2*)q + (tid & 1) * 121;
#define ACC(W, A) { ai += (A).x * hl((W).x) + (A).y * hh((W).x); \
                    af += (A).x * hl((W).y) + (A).y * hh((W).y); \
                    ag += (A).x * hl((W).z) + (A).y * hh((W).z); \
                    ao += (A).x * hl((W).w) + (A).y * hh((W).w); }
            #pragma unroll 1
            for (int kk = 0; kk < 120; kk += 4) {      // 64B-granular weight stream
                uint4 w0 = wp[kk], w1 = wp[kk + 1], w2 = wp[kk + 2], w3 = wp[kk + 3];
                float2 a0 = q2[kk], a1 = q2[kk + 1], a2 = q2[kk + 2], a3 = q2[kk + 3];
                ACC(w0, a0) ACC(w1, a1) ACC(w2, a2) ACC(w3, a3)
            }
            { uint4 w0 = wp[120]; float2 a0 = q2[120]; ACC(w0, a0) }
#undef ACC
        }
        // combine k-halves (lanes 2j <-> 2j+1)
        ai += __shfl_xor(ai, 1); af += __shfl_xor(af, 1);
        ag += __shfl_xor(ag, 1); ao += __shfl_xor(ao, 1);

        // RACE FIX (R10): every wave must finish READING q[83..482] (step t's h)
        // before any thread overwrites it with step t+1's h. Round 2 avoided this
        // via h double-buffering; the in-place q update needs this barrier.
        __syncthreads();

        if (zdo && !(tid & 1)) {
            float si = sigm(ai + bi), sf = sigm(af + bfg), so = sigm(ao + bog);
            cs = sf * cs + si * tanh_f(ag + bgg);
            float hv = so * tanh_f(cs);
            q[83 + n] = hv;
            h_s[n]    = hv;
        }
        __syncthreads();   // h ready

        // ============ phase B: out-proj + attention (independent, same h) ============
        if (odo) {
            float acc = bout;
            const float2* h2 = (const float2*)h_s + oks * 25;
            #pragma unroll 5
            for (int m2 = 0; m2 < 25; ++m2) {
                unsigned w = wop[m2];
                float2 hv = h2[m2];
                acc += hv.x * hl(w) + hv.y * hh(w);
            }
            acc += __shfl_down(acc, 4, 8);
            acc += __shfl_down(acc, 2, 8);
            acc += __shfl_down(acc, 1, 8);
            if (oks == 0) out[((size_t)b * TT + t) * OD + oo] = acc;
        }
        float part = 0.f;
        if (ado) {
            #pragma unroll 5
            for (int k2 = aks; k2 < HH; k2 += 8)
                part += h_s[k2] * s_wattn[k2 * 30 + aj];
        }
        part += __shfl_down(part, 4, 8);
        part += __shfl_down(part, 2, 8);
        part += __shfl_down(part, 1, 8);
        if (ado && aks == 0) s_ap[aj] = part + battn;
        // recycle q's w-slot / x-slot for next step (phase-A reads are done)
        if (tid >= 944) q[3 + (tid - 944)] = 0.f;
        if (tid >= 941 && tid < 944 && t + 1 < TT)
            q[tid - 941] = x[((size_t)b * TT + (t + 1)) * 3 + (tid - 941)];
        __syncthreads();   // s_ap ready, w-slot zeroed

        if (tid < KA) {
            s_abk[tid]       = __expf(s_ap[tid]);           // alpha
            s_abk[16 + tid]  = __expf(s_ap[10 + tid]);      // beta
            s_abk[32 + tid] += __expf(s_ap[20 + tid]);      // kappa += exp(k_hat)
        }
        __syncthreads();   // abk ready

        if (tid < clen) {
            float u = (float)tid;
            float phi = 0.f;
            #pragma unroll
            for (int jj = 0; jj < KA; ++jj) {
                float d = s_abk[32 + jj] - u;
                phi += s_abk[jj] * __expf(-s_abk[16 + jj] * d * d);
            }
            atomicAdd(&q[3 + s_c[tid]], phi);               // w scatter for next step
        }
        __syncthreads();   // q ready for next A-phase
    }
}

extern "C" void kernel_launch(void* const* d_in, const int* in_sizes, int n_in,
                              void* d_out, int out_size, void* d_ws, size_t ws_size,
                              hipStream_t stream) {
    (void)in_sizes; (void)n_in; (void)out_size; (void)ws_size;
    const float* x      = (const float*)d_in[0];
    const int*   c      = (const int*)  d_in[1];
    // d_in[2] = x_len (unused by reference)
    const int*   c_len  = (const int*)  d_in[3];
    const float* W_ih   = (const float*)d_in[4];
    const float* W_hh   = (const float*)d_in[5];
    const float* b_lstm = (const float*)d_in[6];
    const float* W_attn = (const float*)d_in[7];
    const float* b_attn = (const float*)d_in[8];
    const float* W_out  = (const float*)d_in[9];
    const float* b_out  = (const float*)d_in[10];
    float* out = (float*)d_out;

    char* p = (char*)d_ws;
    unsigned* Wz = (unsigned*)(p + OFF_WZ);
    unsigned* Wo = (unsigned*)(p + OFF_WO);

    hipLaunchKernelGGL(setup_kernel, dim3(512), dim3(256), 0, stream,
                       W_ih, W_hh, W_out, Wz, Wo);
    hipLaunchKernelGGL(rnn_main, dim3(BB), dim3(NTH), 0, stream,
                       x, c, c_len, W_attn, b_attn, b_lstm, b_out, Wz, Wo, out);
}

// Round 12
// 11055.054 us; speedup vs baseline: 4.8266x; 1.5224x over previous
//
#include <hip/hip_runtime.h>
#include <stdint.h>

// Graves handwriting RNN — batch-parallel persistent blocks, ZERO grid sync.
// R11 passed (absmax 0.0039 = output floor) at 28 us/step, VALUBusy 20%:
// latency-stalled on a SCATTERED weight stream (64 lines/wave-load).
// R12: (1) coalesced Wz[kk][tid] layout (16 lines/wave-load, all used),
//      (2) depth-4 register prefetch pipeline,
//      (3) out-proj(t-1) overlapped under phase A on idle waves 13-14.
// B=128 T=600 U=50 H=400 V=80 K=10 OUT=121
#define BB   128
#define TT   600
#define UU   50
#define VV   80
#define KA   10
#define OD   121
#define HH   400
#define NTH  1024
#define KKS  132      // kk slots in Wz (128 loop + 4 prefetch overrun; 121 used)

// workspace layout (bytes)
// Wz : [132][800] uint4  = 1,689,600   (fp16x2-packed z-weights, coalesced)
// Wo : [200][128] u32    =   102,400   (fp16x2-packed W_out, coalesced)
#define OFF_WZ   0
#define OFF_WO   1689600

__device__ __forceinline__ unsigned short f2h(float f) {     // fp32 -> fp16 (RNE)
    _Float16 h = (_Float16)f;
    unsigned short us; __builtin_memcpy(&us, &h, 2); return us;
}
__device__ __forceinline__ float hl(unsigned u) {            // low fp16 -> fp32
    unsigned short us = (unsigned short)(u & 0xffffu);
    _Float16 h; __builtin_memcpy(&h, &us, 2); return (float)h;
}
__device__ __forceinline__ float hh(unsigned u) {            // high fp16 -> fp32
    unsigned short us = (unsigned short)(u >> 16);
    _Float16 h; __builtin_memcpy(&h, &us, 2); return (float)h;
}
__device__ __forceinline__ float sigm(float v)   { return 1.f / (1.f + __expf(-v)); }
__device__ __forceinline__ float tanh_f(float v) { return 1.f - 2.f / (__expf(2.f * v) + 1.f); }

// ---------------- setup: pack weights to coalesced fp16 streams ----------------
__global__ void setup_kernel(const float* __restrict__ W_ih, const float* __restrict__ W_hh,
                             const float* __restrict__ W_out,
                             unsigned* __restrict__ Wz, unsigned* __restrict__ Wo)
{
    const int NWZ = KKS * 800 * 4;        // 422,400 u32
    const int NWO = 200 * 128;            //  25,600 u32
    const int total = NWZ + NWO;
    for (int i = blockIdx.x * blockDim.x + threadIdx.x; i < total; i += gridDim.x * blockDim.x) {
        if (i < NWZ) {
            int kk  = i / 3200;           // 800 tid * 4 gates
            int r   = i - kk * 3200;
            int tid = r >> 2, g = r & 3;
            int n   = tid >> 1, hf = tid & 1;
            int col = g * 400 + n;
            unsigned v = 0u;
            if (kk < 121) {
                int k0 = hf * 242 + 2 * kk;
                int k1 = k0 + 1;
                // concat rows: 0..2 = x (W_ih 0..2), 3..82 = w (W_ih 3..82),
                // 83..482 = h (W_hh 0..399), 483 = zero pad
                float s0 = (k0 < 83) ? W_ih[k0 * 1600 + col] : (k0 < 483 ? W_hh[(k0 - 83) * 1600 + col] : 0.f);
                float s1 = (k1 < 83) ? W_ih[k1 * 1600 + col] : (k1 < 483 ? W_hh[(k1 - 83) * 1600 + col] : 0.f);
                v = (unsigned)f2h(s0) | ((unsigned)f2h(s1) << 16);
            }
            Wz[i] = v;                    // u32 index = (kk*800 + tid)*4 + g
        } else {
            int j = i - NWZ;
            int m = j >> 7, oo = j & 127; // m = k-pair 0..199
            unsigned v = 0u;
            if (oo < OD)
                v = (unsigned)f2h(W_out[(2 * m) * OD + oo])
                  | ((unsigned)f2h(W_out[(2 * m + 1) * OD + oo]) << 16);
            Wo[j] = v;
        }
    }
}

// ---------------- main: one block per batch, full 600-step loop ----------------
__global__ __launch_bounds__(NTH) void rnn_main(
    const float* __restrict__ x, const int* __restrict__ c, const int* __restrict__ c_len,
    const float* __restrict__ W_attn, const float* __restrict__ b_attn,
    const float* __restrict__ b_lstm, const float* __restrict__ b_out,
    const unsigned* __restrict__ Wz, const unsigned* __restrict__ Wo,
    float* __restrict__ out)
{
    __shared__ float s_wattn[12000];   // [400][30] fp32
    __shared__ float q[512];           // half0: slots 0..241 @ [0..241], pad [242..255]
                                       // half1: slots 242..483 @ [256..497], pad [498..511]
    __shared__ float hbuf[2][HH];      // double-buffered h (fp32) for outproj/attention
    __shared__ float s_ap[32];
    __shared__ float s_abk[48];        // alpha@0 beta@16 kappa@32 (kappa persistent)
    __shared__ float s_x[4];
    __shared__ int   s_c[UU];

    const int b   = blockIdx.x;
    const int tid = threadIdx.x;

    for (int i = tid; i < 12000; i += NTH) s_wattn[i] = W_attn[i];
    if (tid < UU) s_c[tid] = c[b * UU + tid];
    if (tid < 16) s_abk[32 + tid] = 0.f;
    if (tid < 512) q[tid] = 0.f;                 // zero pads + w + h (x overwrites below)
    if (tid >= 512 && tid < 512 + 2 * HH) hbuf[0][tid - 512] = 0.f;   // zero both hbufs
    if (tid < 3) q[tid] = x[((size_t)b * TT + 0) * 3 + tid];
    const int clen = min(c_len[b], UU);

    // z-GEMV identity: tid<800 -> (n = tid>>1, half = tid&1)
    const int  n   = tid >> 1;
    const int  hf  = tid & 1;
    const bool zdo = (tid < 800);
    const uint4* wq = (const uint4*)Wz + tid;    // element kk at wq[kk*800]
    float bi = 0.f, bfg = 0.f, bgg = 0.f, bog = 0.f;
    if (zdo && !hf) {
        bi  = b_lstm[0 * 400 + n];
        bfg = b_lstm[1 * 400 + n];
        bgg = b_lstm[2 * 400 + n];
        bog = b_lstm[3 * 400 + n];
    }
    float cs = 0.f;                     // cell state, register-resident

    // attention identity: tid<240 -> (aj = tid>>3 in [0,30), aks = tid&7)
    const int  aj = tid >> 3, aks = tid & 7;
    const bool ado = (tid < 240);
    const float battn = (ado && aks == 0) ? b_attn[aj] : 0.f;

    // out-proj identity: waves 13-14 only (no divergence inside GEMV waves)
    const int  oo  = tid - 832;
    const bool odo = (tid >= 832 && tid < 832 + OD);
    const float bout = odo ? b_out[oo] : 0.f;
    const unsigned* wop = odo ? (Wo + oo) : Wo;  // element m at wop[m*128]

    __syncthreads();

    for (int t = 0; t < TT; ++t) {
        const int cur = t & 1;
        // ============ P1: z-GEMV  ||  out-proj(t-1)  ||  x(t+1) prefetch ============
        float ai = 0.f, af = 0.f, ag = 0.f, ao = 0.f;
        if (zdo) {
            const float2* q2 = (const float2*)q + hf * 128;
#define ACC(W, A) { ai += (A).x * hl((W).x) + (A).y * hh((W).x); \
                    af += (A).x * hl((W).y) + (A).y * hh((W).y); \
                    ag += (A).x * hl((W).z) + (A).y * hh((W).z); \
                    ao += (A).x * hl((W).w) + (A).y * hh((W).w); }
            uint4 c0 = wq[0], c1 = wq[800], c2 = wq[1600], c3 = wq[2400];
            const uint4* wr = wq + 3200;
            #pragma unroll 1
            for (int kk = 0; kk < 128; kk += 4) {
                uint4 n0 = wr[0], n1 = wr[800], n2 = wr[1600], n3 = wr[2400];
                float2 a0 = q2[kk], a1 = q2[kk + 1], a2 = q2[kk + 2], a3 = q2[kk + 3];
                ACC(c0, a0) ACC(c1, a1) ACC(c2, a2) ACC(c3, a3)
                c0 = n0; c1 = n1; c2 = n2; c3 = n3;
                wr += 3200;
            }
#undef ACC
        } else if (odo) {
            float acc = bout;
            const float2* h2 = (const float2*)hbuf[cur ^ 1];
            #pragma unroll 4
            for (int m = 0; m < 200; ++m) {
                unsigned w = wop[m * 128];
                float2 hv = h2[m];
                acc += hv.x * hl(w) + hv.y * hh(w);
            }
            if (t > 0) out[((size_t)b * TT + (t - 1)) * OD + oo] = acc;
        } else if (tid >= 960 && tid < 963 && t + 1 < TT) {
            s_x[tid - 960] = x[((size_t)b * TT + (t + 1)) * 3 + (tid - 960)];
        }
        // combine k-halves (lanes 2j <-> 2j+1)
        ai += __shfl_xor(ai, 1); af += __shfl_xor(af, 1);
        ag += __shfl_xor(ag, 1); ao += __shfl_xor(ao, 1);

        __syncthreads();   // B1: q/hbuf[prev] reads done, s_x ready

        if (zdo && !hf) {
            float si = sigm(ai + bi), sf = sigm(af + bfg), so = sigm(ao + bog);
            cs = sf * cs + si * tanh_f(ag + bgg);
            float hv = so * tanh_f(cs);
            int kq = 83 + n;
            q[kq < 242 ? kq : kq + 14] = hv;
            hbuf[cur][n] = hv;
        }
        __syncthreads();   // B2: h(t) ready

        // ============ P3: attention dots + housekeeping ============
        float part = 0.f;
        if (ado) {
            #pragma unroll 5
            for (int k2 = aks; k2 < HH; k2 += 8)
                part += hbuf[cur][k2] * s_wattn[k2 * 30 + aj];
        }
        part += __shfl_down(part, 4, 8);
        part += __shfl_down(part, 2, 8);
        part += __shfl_down(part, 1, 8);
        if (ado && aks == 0) s_ap[aj] = part + battn;
        if (tid >= 944) q[3 + (tid - 944)] = 0.f;                      // zero w-slot
        if (tid >= 941 && tid < 944 && t + 1 < TT) q[tid - 941] = s_x[tid - 941];
        __syncthreads();   // B3: s_ap ready, w-slot zeroed, x staged

        if (tid < KA) {
            s_abk[tid]       = __expf(s_ap[tid]);           // alpha
            s_abk[16 + tid]  = __expf(s_ap[10 + tid]);      // beta
            s_abk[32 + tid] += __expf(s_ap[20 + tid]);      // kappa += exp(k_hat)
        }
        __syncthreads();   // B4: abk ready

        if (tid < clen) {
            float u = (float)tid;
            float phi = 0.f;
            #pragma unroll
            for (int jj = 0; jj < KA; ++jj) {
                float d = s_abk[32 + jj] - u;
                phi += s_abk[jj] * __expf(-s_abk[16 + jj] * d * d);
            }
            atomicAdd(&q[3 + s_c[tid]], phi);               // w scatter for next step
        }
        __syncthreads();   // B5: q ready for next A-phase
    }

    // epilogue: out(TT-1) from hbuf[(TT-1)&1]
    if (odo) {
        float acc = bout;
        const float2* h2 = (const float2*)hbuf[(TT - 1) & 1];
        #pragma unroll 4
        for (int m = 0; m < 200; ++m) {
            unsigned w = wop[m * 128];
            float2 hv = h2[m];
            acc += hv.x * hl(w) + hv.y * hh(w);
        }
        out[((size_t)b * TT + (TT - 1)) * OD + oo] = acc;
    }
}

extern "C" void kernel_launch(void* const* d_in, const int* in_sizes, int n_in,
                              void* d_out, int out_size, void* d_ws, size_t ws_size,
                              hipStream_t stream) {
    (void)in_sizes; (void)n_in; (void)out_size; (void)ws_size;
    const float* x      = (const float*)d_in[0];
    const int*   c      = (const int*)  d_in[1];
    // d_in[2] = x_len (unused by reference)
    const int*   c_len  = (const int*)  d_in[3];
    const float* W_ih   = (const float*)d_in[4];
    const float* W_hh   = (const float*)d_in[5];
    const float* b_lstm = (const float*)d_in[6];
    const float* W_attn = (const float*)d_in[7];
    const float* b_attn = (const float*)d_in[8];
    const float* W_out  = (const float*)d_in[9];
    const float* b_out  = (const float*)d_in[10];
    float* out = (float*)d_out;

    char* p = (char*)d_ws;
    unsigned* Wz = (unsigned*)(p + OFF_WZ);
    unsigned* Wo = (unsigned*)(p + OFF_WO);

    hipLaunchKernelGGL(setup_kernel, dim3(512), dim3(256), 0, stream,
                       W_ih, W_hh, W_out, Wz, Wo);
    hipLaunchKernelGGL(rnn_main, dim3(BB), dim3(NTH), 0, stream,
                       x, c, c_len, W_attn, b_attn, b_lstm, b_out, Wz, Wo, out);
}